// Round 2
// baseline (528.518 us; speedup 1.0000x reference)
//
#include <hip/hip_runtime.h>
#include <stdint.h>
#include <stddef.h>

typedef __bf16 bf16;
typedef __bf16 bf16x4 __attribute__((ext_vector_type(4)));
typedef __bf16 bf16x8 __attribute__((ext_vector_type(8)));
typedef float f32x4 __attribute__((ext_vector_type(4)));

#define MFMA(a, b, c) __builtin_amdgcn_mfma_f32_16x16x32_bf16(a, b, c, 0, 0, 0)

static constexpr int kB = 4, kN = 4096, kC = 1024, kH = 16, kD = 64;
static constexpr int kM = kB * kN;   // 16384 token rows
static constexpr int kK = 1024;      // contraction dim for both GEMMs
static constexpr int kQKVN = 3072;

// async 16B global->LDS (direct-to-LDS DMA; dest = wave-uniform base + lane*16)
__device__ __forceinline__ void cp16(const void* g, void* l) {
  __builtin_amdgcn_global_load_lds(
      (const __attribute__((address_space(1))) void*)g,
      (__attribute__((address_space(3))) void*)l, 16, 0, 0);
}

// fp32 -> bf16 elementwise convert, 4 elems/thread
__global__ __launch_bounds__(256) void cvt_bf16(const float* __restrict__ src,
                                                bf16* __restrict__ dst, int n4) {
  const int i = blockIdx.x * 256 + threadIdx.x;
  if (i < n4) {
    const float4 v = ((const float4*)src)[i];
    bf16x4 o = {(bf16)v.x, (bf16)v.y, (bf16)v.z, (bf16)v.w};
    *(bf16x4*)&dst[4 * i] = o;
  }
}

// rope on 8 consecutive d-elements (4 aligned pairs)
__device__ __forceinline__ bf16x8 rope8(bf16x8 t, bf16x8 f) {
  bf16x8 o;
#pragma unroll
  for (int p = 0; p < 4; ++p) {
    float t0 = (float)t[2 * p], t1 = (float)t[2 * p + 1];
    float f0 = (float)f[2 * p], f1 = (float)f[2 * p + 1];
    o[2 * p]     = (bf16)(t0 * f0 - t1 * f1);
    o[2 * p + 1] = (bf16)(t1 * f0 + t0 * f1);
  }
  return o;
}

// C[m][n] = sum_k A[m][k] * Bw[n][k] (+ bias[n]).  A: kM x kK, Bw: NOUT x kK (both bf16 row-major).
// 128x128 tile, BK=32, 4 waves in 2x2, k8-blocked LDS: [kblk][row][8] -> conflict-free b128
// reads AND global_load_lds-compatible staging (base + lane*16).
template <int NOUT, bool BIAS, typename OutT>
__global__ __launch_bounds__(256) void gemm_bt(const bf16* __restrict__ A,
                                               const bf16* __restrict__ Bw,
                                               const float* __restrict__ bias,
                                               OutT* __restrict__ Cout) {
  __shared__ unsigned short A8[4 * 128 * 8];
  __shared__ unsigned short B8[4 * 128 * 8];
  const int tid = threadIdx.x;
  const int wave = tid >> 6, lane = tid & 63;
  const int q4 = lane >> 4, l16 = lane & 15;
  const int wr = wave >> 1, wc = wave & 1;
  const int n0 = blockIdx.x * 128, m0 = blockIdx.y * 128;

  f32x4 acc[4][4] = {};

  for (int kt = 0; kt < kK / 32; ++kt) {
    const int k0 = kt * 32;
    __syncthreads();
#pragma unroll
    for (int i = 0; i < 2; ++i) {
      const int c = i * 256 + tid;
      const int row = c & 127, kb = c >> 7;  // per wave: kb uniform, row = base + lane
      cp16(A + (size_t)(m0 + row) * kK + k0 + kb * 8, &A8[(kb * 128 + row) * 8]);
      cp16(Bw + (size_t)(n0 + row) * kK + k0 + kb * 8, &B8[(kb * 128 + row) * 8]);
    }
    __syncthreads();
    bf16x8 a[4], b[4];
#pragma unroll
    for (int i = 0; i < 4; ++i)
      a[i] = *(const bf16x8*)&A8[(q4 * 128 + wr * 64 + i * 16 + l16) * 8];
#pragma unroll
    for (int j = 0; j < 4; ++j)
      b[j] = *(const bf16x8*)&B8[(q4 * 128 + wc * 64 + j * 16 + l16) * 8];
#pragma unroll
    for (int i = 0; i < 4; ++i)
#pragma unroll
      for (int j = 0; j < 4; ++j) acc[i][j] = MFMA(a[i], b[j], acc[i][j]);
  }

  // epilogue: C/D layout col=lane&15, row=(lane>>4)*4+reg
#pragma unroll
  for (int i = 0; i < 4; ++i) {
    const int rowb = m0 + wr * 64 + i * 16 + q4 * 4;
#pragma unroll
    for (int j = 0; j < 4; ++j) {
      const int col = n0 + wc * 64 + j * 16 + l16;
      const float bv = BIAS ? bias[col] : 0.0f;
#pragma unroll
      for (int r = 0; r < 4; ++r)
        Cout[(size_t)(rowb + r) * NOUT + col] = (OutT)(acc[i][j][r] + bv);
    }
  }
}

// One block per (b,h,w) window. 4 waves x 64 q-rows, q-groups of 16 rows.
// Flash-style over 2 key-chunks of 128 tokens; softmax stats + O in registers.
__global__ __launch_bounds__(256) void attn_win(const bf16* __restrict__ qkv,
                                                const bf16* __restrict__ freqs,
                                                bf16* __restrict__ ob) {
  __shared__ unsigned short k8[8 * 128 * 8];     // [dblk][tok][8]   16 KB (roped K)
  __shared__ unsigned short v8[16 * 64 * 8];     // [tokblk][d][8]   16 KB (V transposed)
  __shared__ unsigned short p8[4 * 16 * 16 * 8]; // [wave][tokblk][qrow][8] (P round-trip)

  const int bid = blockIdx.x;
  const int w = bid & 15, h = (bid >> 4) & 15, b = bid >> 8;
  const int n0 = w * 256;
  const int tid = threadIdx.x;
  const int wave = tid >> 6, lane = tid & 63;
  const int q4 = lane >> 4, l16 = lane & 15;
  const float scale = 0.125f;  // D^-0.5

  f32x4 O[4][4] = {};          // [group][d-tile]
  float mrow[4][4], lrow[4][4];
#pragma unroll
  for (int g = 0; g < 4; ++g)
#pragma unroll
    for (int r = 0; r < 4; ++r) { mrow[g][r] = -3.0e38f; lrow[g][r] = 0.0f; }

  for (int c = 0; c < 2; ++c) {
    const int nc = n0 + c * 128;
    __syncthreads();  // previous chunk's PV reads done before restaging
#pragma unroll
    for (int i = 0; i < 4; ++i) {
      const int cid = i * 256 + tid;
      const int tok = cid & 127, db = cid >> 7;
      const int n = nc + tok;
      const size_t base = (size_t)(b * kN + n) * kQKVN + h * kD + db * 8;
      bf16x8 kv = *(const bf16x8*)(qkv + base + kC);  // K slice
      bf16x8 fv = *(const bf16x8*)(freqs + (size_t)n * kD + db * 8);
      *(bf16x8*)&k8[(db * 128 + tok) * 8] = rope8(kv, fv);
      bf16x8 vv = *(const bf16x8*)(qkv + base + 2 * kC);  // V slice
#pragma unroll
      for (int e = 0; e < 8; ++e)
        ((bf16*)v8)[((tok >> 3) * 64 + db * 8 + e) * 8 + (tok & 7)] = vv[e];
    }
    __syncthreads();

#pragma unroll
    for (int g = 0; g < 4; ++g) {
      // q fragments with rope (A-layout: row=lane&15, k=(lane>>4)*8+j)
      bf16x8 qf[2];
      {
        const int n = n0 + wave * 64 + g * 16 + l16;
        const bf16* qrow = qkv + (size_t)(b * kN + n) * kQKVN + h * kD;
        const bf16* frow = freqs + (size_t)n * kD;
#pragma unroll
        for (int s = 0; s < 2; ++s) {
          const int d0 = s * 32 + q4 * 8;
          qf[s] = rope8(*(const bf16x8*)(qrow + d0), *(const bf16x8*)(frow + d0));
        }
      }
      // S = Q K^T over d=64 (2 k-steps), 8 col-tiles of 16 tokens
      f32x4 S[8] = {};
#pragma unroll
      for (int j = 0; j < 8; ++j)
#pragma unroll
        for (int s = 0; s < 2; ++s) {
          bf16x8 kf = *(const bf16x8*)&k8[((q4 + 4 * s) * 128 + j * 16 + l16) * 8];
          S[j] = MFMA(qf[s], kf, S[j]);
        }
      // scale + per-row max (16 lanes of a quad-row hold the row's 16-token slices)
      float mx[4], sm[4], al[4];
#pragma unroll
      for (int r = 0; r < 4; ++r) {
        float m = -3.0e38f;
#pragma unroll
        for (int j = 0; j < 8; ++j) { S[j][r] *= scale; m = fmaxf(m, S[j][r]); }
        mx[r] = m;
      }
#pragma unroll
      for (int off = 1; off < 16; off <<= 1)
#pragma unroll
        for (int r = 0; r < 4; ++r) mx[r] = fmaxf(mx[r], __shfl_xor(mx[r], off));
#pragma unroll
      for (int r = 0; r < 4; ++r) {
        const float mnew = fmaxf(mrow[g][r], mx[r]);
        al[r] = __expf(mrow[g][r] - mnew);
        mrow[g][r] = mnew;
        sm[r] = 0.0f;
      }
#pragma unroll
      for (int j = 0; j < 8; ++j)
#pragma unroll
        for (int r = 0; r < 4; ++r) {
          const float p = __expf(S[j][r] - mrow[g][r]);
          S[j][r] = p;
          sm[r] += p;
        }
#pragma unroll
      for (int off = 1; off < 16; off <<= 1)
#pragma unroll
        for (int r = 0; r < 4; ++r) sm[r] += __shfl_xor(sm[r], off);
#pragma unroll
      for (int r = 0; r < 4; ++r) lrow[g][r] = lrow[g][r] * al[r] + sm[r];
#pragma unroll
      for (int jd = 0; jd < 4; ++jd)
#pragma unroll
        for (int r = 0; r < 4; ++r) O[g][jd][r] *= al[r];
      // P: C-layout -> A-layout via per-wave LDS region
#pragma unroll
      for (int j = 0; j < 8; ++j) {
        const int tok = j * 16 + l16;
        const int tb = tok >> 3, slot = tok & 7;
#pragma unroll
        for (int r = 0; r < 4; ++r)
          ((bf16*)p8)[((wave * 16 + tb) * 16 + q4 * 4 + r) * 8 + slot] = (bf16)S[j][r];
      }
      asm volatile("s_waitcnt lgkmcnt(0)" ::: "memory");  // P writes visible (same wave)
      // O += P V  (32 tokens/step x 4 steps over 128-chunk)
#pragma unroll
      for (int s4 = 0; s4 < 4; ++s4) {
        bf16x8 pf = *(const bf16x8*)&p8[((wave * 16 + q4 + 4 * s4) * 16 + l16) * 8];
#pragma unroll
        for (int jd = 0; jd < 4; ++jd) {
          bf16x8 vf = *(const bf16x8*)&v8[((q4 + 4 * s4) * 64 + l16 + 16 * jd) * 8];
          O[g][jd] = MFMA(pf, vf, O[g][jd]);
        }
      }
      asm volatile("" ::: "memory");  // keep next g's p8 writes after this g's reads
    }
  }

  // epilogue: normalize, write attn output rows (b,n) x cols (h*64+d), bf16
#pragma unroll
  for (int g = 0; g < 4; ++g) {
    const int nb = n0 + wave * 64 + g * 16 + q4 * 4;
#pragma unroll
    for (int jd = 0; jd < 4; ++jd) {
      const int d = l16 + 16 * jd;
#pragma unroll
      for (int r = 0; r < 4; ++r) {
        const float v = O[g][jd][r] / lrow[g][r];
        ob[(size_t)(b * kN + nb + r) * kC + h * kD + d] = (bf16)v;
      }
    }
  }
}

extern "C" void kernel_launch(void* const* d_in, const int* in_sizes, int n_in,
                              void* d_out, int out_size, void* d_ws, size_t ws_size,
                              hipStream_t stream) {
  (void)in_sizes; (void)n_in; (void)out_size; (void)ws_size;
  const float* x      = (const float*)d_in[0];
  const float* freqs  = (const float*)d_in[1];
  const float* qkv_w  = (const float*)d_in[2];
  const float* proj_w = (const float*)d_in[3];
  const float* proj_b = (const float*)d_in[4];
  float* out = (float*)d_out;

  // workspace layout (bf16 elems):
  //  [qkv_buf: kM*kQKVN][shared: kM*kC (x_bf16 then attn_buf)][qkvw][projw][freqs]
  bf16* qkv_buf = (bf16*)d_ws;
  bf16* shared  = qkv_buf + (size_t)kM * kQKVN;
  bf16* x_b     = shared;                     // live: convert -> gemm1
  bf16* attn_b  = shared;                     // live: attn -> gemm2
  bf16* qkvw_b  = shared + (size_t)kM * kC;
  bf16* projw_b = qkvw_b + (size_t)kQKVN * kC;
  bf16* freqs_b = projw_b + (size_t)kC * kC;

  // fp32 -> bf16 conversions
  cvt_bf16<<<(kM * kC / 4 + 255) / 256, 256, 0, stream>>>(x, x_b, kM * kC / 4);
  cvt_bf16<<<(kQKVN * kC / 4 + 255) / 256, 256, 0, stream>>>(qkv_w, qkvw_b, kQKVN * kC / 4);
  cvt_bf16<<<(kC * kC / 4 + 255) / 256, 256, 0, stream>>>(proj_w, projw_b, kC * kC / 4);
  cvt_bf16<<<(kN * kD / 4 + 255) / 256, 256, 0, stream>>>(freqs, freqs_b, kN * kD / 4);

  gemm_bt<kQKVN, false, bf16><<<dim3(kQKVN / 128, kM / 128), 256, 0, stream>>>(
      x_b, qkvw_b, nullptr, qkv_buf);
  attn_win<<<dim3(kB * kH * (kN / 256)), 256, 0, stream>>>(qkv_buf, freqs_b, attn_b);
  gemm_bt<kC, true, float><<<dim3(kC / 128, kM / 128), 256, 0, stream>>>(
      attn_b, projw_b, proj_b, out);
}

// Round 3
// 521.569 us; speedup vs baseline: 1.0133x; 1.0133x over previous
//
#include <hip/hip_runtime.h>
#include <stdint.h>
#include <stddef.h>

typedef __bf16 bf16;
typedef __bf16 bf16x4 __attribute__((ext_vector_type(4)));
typedef __bf16 bf16x8 __attribute__((ext_vector_type(8)));
typedef float f32x4 __attribute__((ext_vector_type(4)));

#define MFMA(a, b, c) __builtin_amdgcn_mfma_f32_16x16x32_bf16(a, b, c, 0, 0, 0)

static constexpr int kB = 4, kN = 4096, kC = 1024, kH = 16, kD = 64;
static constexpr int kM = kB * kN;   // 16384 token rows
static constexpr int kK = 1024;      // contraction dim for both GEMMs
static constexpr int kQKVN = 3072;

// async 16B global->LDS (direct-to-LDS DMA; dest = wave-uniform base + lane*16)
__device__ __forceinline__ void cp16(const void* g, void* l) {
  __builtin_amdgcn_global_load_lds(
      (const __attribute__((address_space(1))) void*)g,
      (__attribute__((address_space(3))) void*)l, 16, 0, 0);
}

// fp32 -> bf16 elementwise convert, 4 elems/thread
__global__ __launch_bounds__(256) void cvt_bf16(const float* __restrict__ src,
                                                bf16* __restrict__ dst, int n4) {
  const int i = blockIdx.x * 256 + threadIdx.x;
  if (i < n4) {
    const float4 v = ((const float4*)src)[i];
    bf16x4 o = {(bf16)v.x, (bf16)v.y, (bf16)v.z, (bf16)v.w};
    *(bf16x4*)&dst[4 * i] = o;
  }
}

// rope on 8 consecutive d-elements (4 aligned pairs)
__device__ __forceinline__ bf16x8 rope8(bf16x8 t, bf16x8 f) {
  bf16x8 o;
#pragma unroll
  for (int p = 0; p < 4; ++p) {
    float t0 = (float)t[2 * p], t1 = (float)t[2 * p + 1];
    float f0 = (float)f[2 * p], f1 = (float)f[2 * p + 1];
    o[2 * p]     = (bf16)(t0 * f0 - t1 * f1);
    o[2 * p + 1] = (bf16)(t1 * f0 + t0 * f1);
  }
  return o;
}

// C[m][n] = sum_k A[m][k] * Bw[n][k] (+ bias[n]).  A: kM x kK, Bw: NOUT x kK (bf16 row-major).
// 256x128 tile, BK=32, 4 waves in 2x2 (each 128 rows x 64 cols, acc 8x4), DOUBLE-BUFFERED:
// one barrier per iteration; cp16 for tile k+1 issued before tile k's MFMA section so the
// vmcnt(0) drain at the next barrier lands a full compute-section after issue.
// k8-blocked LDS [kblk][row][8]: conflict-free b128 reads AND cp16-compatible (base+lane*16).
template <int NOUT, bool BIAS, typename OutT>
__global__ __launch_bounds__(256, 2) void gemm_bt(const bf16* __restrict__ A,
                                                  const bf16* __restrict__ Bw,
                                                  const float* __restrict__ bias,
                                                  OutT* __restrict__ Cout) {
  __shared__ unsigned short A8[2][4 * 256 * 8];  // 16 KB per buffer
  __shared__ unsigned short B8[2][4 * 128 * 8];  //  8 KB per buffer
  const int tid = threadIdx.x;
  const int wave = tid >> 6, lane = tid & 63;
  const int q4 = lane >> 4, l16 = lane & 15;
  const int wr = wave >> 1, wc = wave & 1;
  const int n0 = blockIdx.x * 128, m0 = blockIdx.y * 256;

  f32x4 acc[8][4] = {};

  auto stage = [&](int kt, int buf) {
    const int k0 = kt * 32;
#pragma unroll
    for (int i = 0; i < 4; ++i) {  // A: 256 rows x 32k = 1024 16B chunks
      const int c = i * 256 + tid;
      const int row = c & 255, kb = c >> 8;  // per-wave: kb uniform, row = base + lane
      cp16(A + (size_t)(m0 + row) * kK + k0 + kb * 8, &A8[buf][(kb * 256 + row) * 8]);
    }
#pragma unroll
    for (int i = 0; i < 2; ++i) {  // B: 128 rows x 32k = 512 chunks
      const int c = i * 256 + tid;
      const int row = c & 127, kb = c >> 7;
      cp16(Bw + (size_t)(n0 + row) * kK + k0 + kb * 8, &B8[buf][(kb * 128 + row) * 8]);
    }
  };

  constexpr int NT = kK / 32;
  stage(0, 0);
  for (int kt = 0; kt < NT; ++kt) {
    const int buf = kt & 1;
    // drains this wave's cp16s for tile kt (vmcnt) and everyone's reads of buf^1 (lgkm)
    __syncthreads();
    if (kt + 1 < NT) stage(kt + 1, buf ^ 1);
    bf16x8 a[8], b[4];
#pragma unroll
    for (int i = 0; i < 8; ++i)
      a[i] = *(const bf16x8*)&A8[buf][(q4 * 256 + wr * 128 + i * 16 + l16) * 8];
#pragma unroll
    for (int j = 0; j < 4; ++j)
      b[j] = *(const bf16x8*)&B8[buf][(q4 * 128 + wc * 64 + j * 16 + l16) * 8];
#pragma unroll
    for (int i = 0; i < 8; ++i)
#pragma unroll
      for (int j = 0; j < 4; ++j) acc[i][j] = MFMA(a[i], b[j], acc[i][j]);
  }

  // epilogue: C/D layout col=lane&15, row=(lane>>4)*4+reg
#pragma unroll
  for (int i = 0; i < 8; ++i) {
    const int rowb = m0 + wr * 128 + i * 16 + q4 * 4;
#pragma unroll
    for (int j = 0; j < 4; ++j) {
      const int col = n0 + wc * 64 + j * 16 + l16;
      const float bv = BIAS ? bias[col] : 0.0f;
#pragma unroll
      for (int r = 0; r < 4; ++r)
        Cout[(size_t)(rowb + r) * NOUT + col] = (OutT)(acc[i][j][r] + bv);
    }
  }
}

// One block per (b,h,w) window. 4 waves x 64 q-rows, q-groups of 16 rows.
// Flash-style over 2 key-chunks of 128 tokens; softmax stats + O in registers.
__global__ __launch_bounds__(256) void attn_win(const bf16* __restrict__ qkv,
                                                const bf16* __restrict__ freqs,
                                                bf16* __restrict__ ob) {
  __shared__ unsigned short k8[8 * 128 * 8];     // [dblk][tok][8]   16 KB (roped K)
  __shared__ unsigned short v8[16 * 64 * 8];     // [tokblk][d][8]   16 KB (V transposed)
  __shared__ unsigned short p8[4 * 16 * 16 * 8]; // [wave][tokblk][qrow][8] (P round-trip)

  const int bid = blockIdx.x;
  const int w = bid & 15, h = (bid >> 4) & 15, b = bid >> 8;
  const int n0 = w * 256;
  const int tid = threadIdx.x;
  const int wave = tid >> 6, lane = tid & 63;
  const int q4 = lane >> 4, l16 = lane & 15;
  const float scale = 0.125f;  // D^-0.5

  // q fragments with rope, hoisted: reused across both key-chunks
  // (A-layout: row=lane&15, k=(lane>>4)*8+j)
  bf16x8 qf[4][2];
#pragma unroll
  for (int g = 0; g < 4; ++g) {
    const int n = n0 + wave * 64 + g * 16 + l16;
    const bf16* qrow = qkv + (size_t)(b * kN + n) * kQKVN + h * kD;
    const bf16* frow = freqs + (size_t)n * kD;
#pragma unroll
    for (int s = 0; s < 2; ++s) {
      const int d0 = s * 32 + q4 * 8;
      qf[g][s] = rope8(*(const bf16x8*)(qrow + d0), *(const bf16x8*)(frow + d0));
    }
  }

  f32x4 O[4][4] = {};          // [group][d-tile]
  float mrow[4][4], lrow[4][4];
#pragma unroll
  for (int g = 0; g < 4; ++g)
#pragma unroll
    for (int r = 0; r < 4; ++r) { mrow[g][r] = -3.0e38f; lrow[g][r] = 0.0f; }

  for (int c = 0; c < 2; ++c) {
    const int nc = n0 + c * 128;
    __syncthreads();  // previous chunk's PV reads done before restaging
#pragma unroll
    for (int i = 0; i < 4; ++i) {
      const int cid = i * 256 + tid;
      const int tok = cid & 127, db = cid >> 7;
      const int n = nc + tok;
      const size_t base = (size_t)(b * kN + n) * kQKVN + h * kD + db * 8;
      bf16x8 kv = *(const bf16x8*)(qkv + base + kC);  // K slice
      bf16x8 fv = *(const bf16x8*)(freqs + (size_t)n * kD + db * 8);
      *(bf16x8*)&k8[(db * 128 + tok) * 8] = rope8(kv, fv);
      bf16x8 vv = *(const bf16x8*)(qkv + base + 2 * kC);  // V slice
#pragma unroll
      for (int e = 0; e < 8; ++e)
        ((bf16*)v8)[((tok >> 3) * 64 + db * 8 + e) * 8 + (tok & 7)] = vv[e];
    }
    __syncthreads();

#pragma unroll
    for (int g = 0; g < 4; ++g) {
      // S = Q K^T over d=64 (2 k-steps), 8 col-tiles of 16 tokens
      f32x4 S[8] = {};
#pragma unroll
      for (int j = 0; j < 8; ++j)
#pragma unroll
        for (int s = 0; s < 2; ++s) {
          bf16x8 kf = *(const bf16x8*)&k8[((q4 + 4 * s) * 128 + j * 16 + l16) * 8];
          S[j] = MFMA(qf[g][s], kf, S[j]);
        }
      // scale + per-row max (16 lanes of a quad-row hold the row's 16-token slices)
      float mx[4], sm[4], al[4];
#pragma unroll
      for (int r = 0; r < 4; ++r) {
        float m = -3.0e38f;
#pragma unroll
        for (int j = 0; j < 8; ++j) { S[j][r] *= scale; m = fmaxf(m, S[j][r]); }
        mx[r] = m;
      }
#pragma unroll
      for (int off = 1; off < 16; off <<= 1)
#pragma unroll
        for (int r = 0; r < 4; ++r) mx[r] = fmaxf(mx[r], __shfl_xor(mx[r], off));
#pragma unroll
      for (int r = 0; r < 4; ++r) {
        const float mnew = fmaxf(mrow[g][r], mx[r]);
        al[r] = __expf(mrow[g][r] - mnew);
        mrow[g][r] = mnew;
        sm[r] = 0.0f;
      }
#pragma unroll
      for (int j = 0; j < 8; ++j)
#pragma unroll
        for (int r = 0; r < 4; ++r) {
          const float p = __expf(S[j][r] - mrow[g][r]);
          S[j][r] = p;
          sm[r] += p;
        }
#pragma unroll
      for (int off = 1; off < 16; off <<= 1)
#pragma unroll
        for (int r = 0; r < 4; ++r) sm[r] += __shfl_xor(sm[r], off);
#pragma unroll
      for (int r = 0; r < 4; ++r) lrow[g][r] = lrow[g][r] * al[r] + sm[r];
#pragma unroll
      for (int jd = 0; jd < 4; ++jd)
#pragma unroll
        for (int r = 0; r < 4; ++r) O[g][jd][r] *= al[r];
      // P: C-layout -> A-layout via per-wave LDS region
#pragma unroll
      for (int j = 0; j < 8; ++j) {
        const int tok = j * 16 + l16;
        const int tb = tok >> 3, slot = tok & 7;
#pragma unroll
        for (int r = 0; r < 4; ++r)
          ((bf16*)p8)[((wave * 16 + tb) * 16 + q4 * 4 + r) * 8 + slot] = (bf16)S[j][r];
      }
      asm volatile("s_waitcnt lgkmcnt(0)" ::: "memory");  // P writes visible (same wave)
      // O += P V  (32 tokens/step x 4 steps over 128-chunk)
#pragma unroll
      for (int s4 = 0; s4 < 4; ++s4) {
        bf16x8 pf = *(const bf16x8*)&p8[((wave * 16 + q4 + 4 * s4) * 16 + l16) * 8];
#pragma unroll
        for (int jd = 0; jd < 4; ++jd) {
          bf16x8 vf = *(const bf16x8*)&v8[((q4 + 4 * s4) * 64 + l16 + 16 * jd) * 8];
          O[g][jd] = MFMA(pf, vf, O[g][jd]);
        }
      }
      asm volatile("" ::: "memory");  // keep next g's p8 writes after this g's reads
    }
  }

  // epilogue: normalize, write attn output rows (b,n) x cols (h*64+d), bf16
#pragma unroll
  for (int g = 0; g < 4; ++g) {
    const int nb = n0 + wave * 64 + g * 16 + q4 * 4;
#pragma unroll
    for (int jd = 0; jd < 4; ++jd) {
      const int d = l16 + 16 * jd;
#pragma unroll
      for (int r = 0; r < 4; ++r) {
        const float v = O[g][jd][r] / lrow[g][r];
        ob[(size_t)(b * kN + nb + r) * kC + h * kD + d] = (bf16)v;
      }
    }
  }
}

extern "C" void kernel_launch(void* const* d_in, const int* in_sizes, int n_in,
                              void* d_out, int out_size, void* d_ws, size_t ws_size,
                              hipStream_t stream) {
  (void)in_sizes; (void)n_in; (void)out_size; (void)ws_size;
  const float* x      = (const float*)d_in[0];
  const float* freqs  = (const float*)d_in[1];
  const float* qkv_w  = (const float*)d_in[2];
  const float* proj_w = (const float*)d_in[3];
  const float* proj_b = (const float*)d_in[4];
  float* out = (float*)d_out;

  // workspace layout (bf16 elems):
  //  [qkv_buf: kM*kQKVN][shared: kM*kC (x_bf16 then attn_buf)][qkvw][projw][freqs]
  bf16* qkv_buf = (bf16*)d_ws;
  bf16* shared  = qkv_buf + (size_t)kM * kQKVN;
  bf16* x_b     = shared;                     // live: convert -> gemm1
  bf16* attn_b  = shared;                     // live: attn -> gemm2
  bf16* qkvw_b  = shared + (size_t)kM * kC;
  bf16* projw_b = qkvw_b + (size_t)kQKVN * kC;
  bf16* freqs_b = projw_b + (size_t)kC * kC;

  // fp32 -> bf16 conversions
  cvt_bf16<<<(kM * kC / 4 + 255) / 256, 256, 0, stream>>>(x, x_b, kM * kC / 4);
  cvt_bf16<<<(kQKVN * kC / 4 + 255) / 256, 256, 0, stream>>>(qkv_w, qkvw_b, kQKVN * kC / 4);
  cvt_bf16<<<(kC * kC / 4 + 255) / 256, 256, 0, stream>>>(proj_w, projw_b, kC * kC / 4);
  cvt_bf16<<<(kN * kD / 4 + 255) / 256, 256, 0, stream>>>(freqs, freqs_b, kN * kD / 4);

  gemm_bt<kQKVN, false, bf16><<<dim3(kQKVN / 128, kM / 256), 256, 0, stream>>>(
      x_b, qkvw_b, nullptr, qkv_buf);
  attn_win<<<dim3(kB * kH * (kN / 256)), 256, 0, stream>>>(qkv_buf, freqs_b, attn_b);
  gemm_bt<kC, true, float><<<dim3(kC / 128, kM / 256), 256, 0, stream>>>(
      attn_b, projw_b, proj_b, out);
}